// Round 5
// baseline (169.551 us; speedup 1.0000x reference)
//
#include <hip/hip_runtime.h>

#define NH    8
#define BROWS 32768
#define INF   16
#define CIN   32
#define OUTF  32
#define KTOT  544   // OUTF*(INF+1)

#define BLKX  128                  // blocks per head -> 1024 total (4/CU)
#define WPH   (BLKX * 4)           // worker waves per head = 512
#define UNITS (BROWS / 32)         // 32-sample units per head = 1024

typedef __attribute__((ext_vector_type(8))) short short8;
typedef __attribute__((ext_vector_type(4))) float floatx4;

__device__ __forceinline__ short f2bf(float f) {
    __bf16 h = (__bf16)f;   // RNE f32->bf16
    return __builtin_bit_cast(short, h);
}

// Grid: (128, 8). Block: 256 threads = 4 independent waves.
// W (one head, bf16) staged cooperatively into LDS: 17 i x 2 otiles x 64 lanes
// x 16B = 34816 B. Each wave covers ALL 32 outputs for its 16-sample tiles
// (2 tiles per iteration for ILP), so each wave writes full 128B out-lines.
// Swapped MFMA: D[m=o][n=b] = W_i x cond^T; per-sample scale x1[b,i] applied
// to D (lane-local). Bias term = accumulator-init MFMA. Nontemporal stores.
__global__ __launch_bounds__(256, 4) void meta_multilinear(
    const float* __restrict__ input,
    const float* __restrict__ cond,
    const float* __restrict__ weight,
    const float* __restrict__ bias,
    float* __restrict__ out)
{
    __shared__ short8 lds_w[17 * 2 * 64];   // [(i*2+ot)*64 + lane], 34816 B

    const int tid   = threadIdx.x;
    const int lane  = tid & 63;
    const int wave  = tid >> 6;     // 0..3
    const int r     = lane & 15;
    const int quad  = lane >> 4;    // 0..3
    const int c0    = quad * 8;     // K-slice start

    const int h = blockIdx.y;

    const float* Wh = weight + (size_t)h * KTOT * CIN;
    const float* bh = bias   + (size_t)h * KTOT;

    // ---- cooperative W staging: f32 -> bf16 -> LDS ----
    // element s: i = s>>7, ot = (s>>6)&1, dest lane sl = s&63 (sr, sq)
    for (int s = tid; s < 17 * 2 * 64; s += 256) {
        const int sl = s & 63;
        const int sr = sl & 15;
        const int sq = sl >> 4;
        const int ot = (s >> 6) & 1;
        const int i  = s >> 7;
        const float* src = Wh + (size_t)((ot * 16 + sr) * 17 + i) * CIN + sq * 8;
        floatx4 w0 = *(const floatx4*)(src);
        floatx4 w1 = *(const floatx4*)(src + 4);
        short8 f;
        f[0]=f2bf(w0.x); f[1]=f2bf(w0.y); f[2]=f2bf(w0.z); f[3]=f2bf(w0.w);
        f[4]=f2bf(w1.x); f[5]=f2bf(w1.y); f[6]=f2bf(w1.z); f[7]=f2bf(w1.w);
        lds_w[s] = f;
    }

    // ---- bias A fragments (both otiles): A[m=o][k=i] = bias[h][o*17+i] ----
    short8 bA0, bA1;
    #pragma unroll
    for (int j = 0; j < 8; ++j) {
        const int i = c0 + j;
        short v0 = 0, v1 = 0;
        if (i < 17) {
            v0 = f2bf(bh[r * 17 + i]);          // exec-masked
            v1 = f2bf(bh[(16 + r) * 17 + i]);
        }
        bA0[j] = v0;
        bA1[j] = v1;
    }

    __syncthreads();

    const float* condh = cond  + (size_t)h * BROWS * CIN;
    const float* inh   = input + (size_t)h * BROWS * INF;
    float*       outh  = out   + (size_t)h * BROWS * OUTF;
    const floatx4 zero = {0.f, 0.f, 0.f, 0.f};

    const int gw = blockIdx.x * 4 + wave;   // 0..511 per head

    for (int u = gw; u < UNITS; u += WPH) { // exactly 2 iterations
        const int ba = u * 32;          // tile A rows [ba, ba+16)
        const int bb = ba + 16;         // tile B rows [bb, bb+16)

        // ---- issue ALL 12 global loads ----
        const float* crowA = condh + (size_t)(ba + r) * CIN + c0;
        floatx4 cAa = *(const floatx4*)(crowA);
        floatx4 cBa = *(const floatx4*)(crowA + 4);
        const float* xrowA = inh + (size_t)(ba + r) * INF;
        floatx4 x0a = *(const floatx4*)(xrowA);
        floatx4 x1a = *(const floatx4*)(xrowA + 4);
        floatx4 x2a = *(const floatx4*)(xrowA + 8);
        floatx4 x3a = *(const floatx4*)(xrowA + 12);

        const float* crowB = condh + (size_t)(bb + r) * CIN + c0;
        floatx4 cAb = *(const floatx4*)(crowB);
        floatx4 cBb = *(const floatx4*)(crowB + 4);
        const float* xrowB = inh + (size_t)(bb + r) * INF;
        floatx4 x0b = *(const floatx4*)(xrowB);
        floatx4 x1b = *(const floatx4*)(xrowB + 4);
        floatx4 x2b = *(const floatx4*)(xrowB + 8);
        floatx4 x3b = *(const floatx4*)(xrowB + 12);

        // ---- cond -> bf16 B fragments ----
        short8 cfa, cfb;
        cfa[0]=f2bf(cAa.x); cfa[1]=f2bf(cAa.y); cfa[2]=f2bf(cAa.z); cfa[3]=f2bf(cAa.w);
        cfa[4]=f2bf(cBa.x); cfa[5]=f2bf(cBa.y); cfa[6]=f2bf(cBa.z); cfa[7]=f2bf(cBa.w);
        cfb[0]=f2bf(cAb.x); cfb[1]=f2bf(cAb.y); cfb[2]=f2bf(cAb.z); cfb[3]=f2bf(cAb.w);
        cfb[4]=f2bf(cBb.x); cfb[5]=f2bf(cBb.y); cfb[6]=f2bf(cBb.z); cfb[7]=f2bf(cBb.w);

        // ---- x1 as B fragment for bias term ----
        #define MAKE_XB(xb, x0, x1, x2, x3) do {                                     \
            if (quad == 0) {                                                         \
                xb[0]=f2bf(x0.x); xb[1]=f2bf(x0.y); xb[2]=f2bf(x0.z); xb[3]=f2bf(x0.w); \
                xb[4]=f2bf(x1.x); xb[5]=f2bf(x1.y); xb[6]=f2bf(x1.z); xb[7]=f2bf(x1.w); \
            } else if (quad == 1) {                                                  \
                xb[0]=f2bf(x2.x); xb[1]=f2bf(x2.y); xb[2]=f2bf(x2.z); xb[3]=f2bf(x2.w); \
                xb[4]=f2bf(x3.x); xb[5]=f2bf(x3.y); xb[6]=f2bf(x3.z); xb[7]=f2bf(x3.w); \
            } else if (quad == 2) {                                                  \
                xb[0]=f2bf(1.0f); xb[1]=0; xb[2]=0; xb[3]=0;                         \
                xb[4]=0; xb[5]=0; xb[6]=0; xb[7]=0;                                  \
            } else {                                                                 \
                xb[0]=0; xb[1]=0; xb[2]=0; xb[3]=0;                                  \
                xb[4]=0; xb[5]=0; xb[6]=0; xb[7]=0;                                  \
            }                                                                        \
        } while (0)
        short8 xba, xbb;
        MAKE_XB(xba, x0a, x1a, x2a, x3a);
        MAKE_XB(xbb, x0b, x1b, x2b, x3b);
        #undef MAKE_XB

        // ---- bias MFMAs initialize accumulators ----
        floatx4 fa0 = __builtin_amdgcn_mfma_f32_16x16x32_bf16(bA0, xba, zero, 0, 0, 0);
        floatx4 fa1 = __builtin_amdgcn_mfma_f32_16x16x32_bf16(bA1, xba, zero, 0, 0, 0);
        floatx4 fb0 = __builtin_amdgcn_mfma_f32_16x16x32_bf16(bA0, xbb, zero, 0, 0, 0);
        floatx4 fb1 = __builtin_amdgcn_mfma_f32_16x16x32_bf16(bA1, xbb, zero, 0, 0, 0);

        // ---- 17 steps: 2 ds_read_b128 + 4 MFMA + 8 pk_fma each ----
        #define STEP(i, sa, sb) do {                                                 \
            short8 w0 = lds_w[(i) * 128 + lane];                                     \
            short8 w1 = lds_w[(i) * 128 + 64 + lane];                                \
            floatx4 d00 = __builtin_amdgcn_mfma_f32_16x16x32_bf16(w0, cfa, zero, 0, 0, 0); \
            floatx4 d01 = __builtin_amdgcn_mfma_f32_16x16x32_bf16(w1, cfa, zero, 0, 0, 0); \
            floatx4 d10 = __builtin_amdgcn_mfma_f32_16x16x32_bf16(w0, cfb, zero, 0, 0, 0); \
            floatx4 d11 = __builtin_amdgcn_mfma_f32_16x16x32_bf16(w1, cfb, zero, 0, 0, 0); \
            fa0 += d00 * (sa); fa1 += d01 * (sa);                                    \
            fb0 += d10 * (sb); fb1 += d11 * (sb);                                    \
        } while (0)
        STEP(0,  x0a.x, x0b.x); STEP(1,  x0a.y, x0b.y);
        STEP(2,  x0a.z, x0b.z); STEP(3,  x0a.w, x0b.w);
        STEP(4,  x1a.x, x1b.x); STEP(5,  x1a.y, x1b.y);
        STEP(6,  x1a.z, x1b.z); STEP(7,  x1a.w, x1b.w);
        STEP(8,  x2a.x, x2b.x); STEP(9,  x2a.y, x2b.y);
        STEP(10, x2a.z, x2b.z); STEP(11, x2a.w, x2b.w);
        STEP(12, x3a.x, x3b.x); STEP(13, x3a.y, x3b.y);
        STEP(14, x3a.z, x3b.z); STEP(15, x3a.w, x3b.w);
        STEP(16, 1.0f,  1.0f);
        #undef STEP

        // ---- stores: each lane writes 2x16B; wave covers full 128B rows ----
        float* da = outh + (size_t)(ba + r) * OUTF + quad * 4;
        __builtin_nontemporal_store(fa0, (floatx4*)da);
        __builtin_nontemporal_store(fa1, (floatx4*)(da + 16));
        float* db = outh + (size_t)(bb + r) * OUTF + quad * 4;
        __builtin_nontemporal_store(fb0, (floatx4*)db);
        __builtin_nontemporal_store(fb1, (floatx4*)(db + 16));
    }
}

extern "C" void kernel_launch(void* const* d_in, const int* in_sizes, int n_in,
                              void* d_out, int out_size, void* d_ws, size_t ws_size,
                              hipStream_t stream) {
    const float* input  = (const float*)d_in[0];
    const float* cond   = (const float*)d_in[1];
    const float* weight = (const float*)d_in[2];
    const float* bias   = (const float*)d_in[3];
    float* out = (float*)d_out;

    dim3 grid(BLKX, NH, 1);
    dim3 block(256, 1, 1);
    hipLaunchKernelGGL(meta_multilinear, grid, block, 0, stream,
                       input, cond, weight, bias, out);
}

// Round 6
// 113.341 us; speedup vs baseline: 1.4959x; 1.4959x over previous
//
#include <hip/hip_runtime.h>

#define NH    8
#define BROWS 32768
#define INF   16
#define CIN   32
#define OUTF  32
#define KTOT  544   // OUTF*(INF+1)

#define BLKX  128                  // blocks per head -> 1024 total (4/CU, LDS-matched)
#define WELEM 2176                 // W image elements (short8) per head: 17*2*64
#define BELEM 128                  // bias frag elements (short8) per head: 2*64

typedef __attribute__((ext_vector_type(8))) short short8;
typedef __attribute__((ext_vector_type(4))) float floatx4;

__device__ __forceinline__ short f2bf(float f) {
    __bf16 h = (__bf16)f;   // RNE f32->bf16
    return __builtin_bit_cast(short, h);
}

// ---------------- prep: W,bias -> bf16 fragment images in d_ws ----------------
// ws layout: [h][s] W image (NH*WELEM short8), then [h][s] bias frags (NH*BELEM).
// W image element s: i = s>>7, ot = (s>>6)&1, lane sl = s&63 (sr = sl&15, sq = sl>>4)
//   holds A[m = ot*16+sr][k = sq*8 .. +8) = W[h][(ot*16+sr)*17 + i][sq*8 ..]
// bias element s: ot = s>>6, lane sl: holds bias[h][(ot*16+sr)*17 + (sq*8+j)], 0 pad i>=17.
__global__ __launch_bounds__(256) void prep_w(
    const float* __restrict__ weight,
    const float* __restrict__ bias,
    short8* __restrict__ ws)
{
    const int q = blockIdx.x;       // quarter 0..3
    const int h = blockIdx.y;
    const float* Wh = weight + (size_t)h * KTOT * CIN;
    short8* dstW = ws + (size_t)h * WELEM;

    for (int s = q * (WELEM / 4) + threadIdx.x; s < (q + 1) * (WELEM / 4); s += 256) {
        const int sl = s & 63;
        const int sr = sl & 15;
        const int sq = sl >> 4;
        const int ot = (s >> 6) & 1;
        const int i  = s >> 7;
        const float* src = Wh + (size_t)((ot * 16 + sr) * 17 + i) * CIN + sq * 8;
        floatx4 w0 = *(const floatx4*)(src);
        floatx4 w1 = *(const floatx4*)(src + 4);
        short8 f;
        f[0]=f2bf(w0.x); f[1]=f2bf(w0.y); f[2]=f2bf(w0.z); f[3]=f2bf(w0.w);
        f[4]=f2bf(w1.x); f[5]=f2bf(w1.y); f[6]=f2bf(w1.z); f[7]=f2bf(w1.w);
        dstW[s] = f;
    }

    if (q == 0) {
        const float* bh = bias + (size_t)h * KTOT;
        short8* dstB = ws + (size_t)NH * WELEM + (size_t)h * BELEM;
        for (int s = threadIdx.x; s < BELEM; s += 256) {
            const int sl = s & 63;
            const int sr = sl & 15;
            const int sq = sl >> 4;
            const int ot = s >> 6;
            const int o  = ot * 16 + sr;
            short8 f;
            #pragma unroll
            for (int j = 0; j < 8; ++j) {
                const int i = sq * 8 + j;
                f[j] = (i < 17) ? f2bf(bh[o * 17 + i]) : (short)0;
            }
            dstB[s] = f;
        }
    }
}

// ---------------- main ----------------
// Grid: (128, 8). Block: 256 threads = 4 independent waves. LDS: 34816 B
// (4 blocks/CU -> 16 waves/CU). Each wave: 4 consecutive 16-sample tiles,
// processed as 2 groups of 2 (12 front-loaded global loads per group for ILP).
// Swapped MFMA: D[m=o][n=b] = W_i x cond^T; per-sample scale x1[b,i] applied to
// D (lane-local). Bias = accumulator-init MFMA. Both otiles per wave -> each
// wave writes full 128B out-lines, nontemporal.
__global__ __launch_bounds__(256) void meta_multilinear(
    const float* __restrict__ input,
    const float* __restrict__ cond,
    const short8* __restrict__ ws,
    float* __restrict__ out)
{
    __shared__ short8 lds_w[WELEM];   // 34816 B

    const int tid  = threadIdx.x;
    const int lane = tid & 63;
    const int wave = tid >> 6;      // 0..3
    const int r    = lane & 15;
    const int quad = lane >> 4;     // 0..3
    const int c0   = quad * 8;      // K-slice start

    const int h = blockIdx.y;

    // ---- coalesced staging of pre-swizzled bf16 W image ----
    const short8* srcW = ws + (size_t)h * WELEM;
    for (int s = tid; s < WELEM; s += 256) lds_w[s] = srcW[s];

    // ---- bias fragments (2 x 16B loads) ----
    const short8* srcB = ws + (size_t)NH * WELEM + (size_t)h * BELEM;
    const short8 bA0 = srcB[lane];
    const short8 bA1 = srcB[64 + lane];

    __syncthreads();

    const float* condh = cond  + (size_t)h * BROWS * CIN;
    const float* inh   = input + (size_t)h * BROWS * INF;
    float*       outh  = out   + (size_t)h * BROWS * OUTF;
    const floatx4 zero = {0.f, 0.f, 0.f, 0.f};

    const int gw = blockIdx.x * 4 + wave;   // 0..511 per head; 4 tiles each

    #pragma unroll 1
    for (int g = 0; g < 2; ++g) {
        const int ba = (gw * 4 + 2 * g) * 16;   // tile A rows
        const int bb = ba + 16;                  // tile B rows

        // ---- issue ALL 12 global loads (tile A then tile B) ----
        const float* crowA = condh + (size_t)(ba + r) * CIN + c0;
        floatx4 cAa = *(const floatx4*)(crowA);
        floatx4 cBa = *(const floatx4*)(crowA + 4);
        const float* xrowA = inh + (size_t)(ba + r) * INF;
        floatx4 x0a = *(const floatx4*)(xrowA);
        floatx4 x1a = *(const floatx4*)(xrowA + 4);
        floatx4 x2a = *(const floatx4*)(xrowA + 8);
        floatx4 x3a = *(const floatx4*)(xrowA + 12);

        const float* crowB = condh + (size_t)(bb + r) * CIN + c0;
        floatx4 cAb = *(const floatx4*)(crowB);
        floatx4 cBb = *(const floatx4*)(crowB + 4);
        const float* xrowB = inh + (size_t)(bb + r) * INF;
        floatx4 x0b = *(const floatx4*)(xrowB);
        floatx4 x1b = *(const floatx4*)(xrowB + 4);
        floatx4 x2b = *(const floatx4*)(xrowB + 8);
        floatx4 x3b = *(const floatx4*)(xrowB + 12);

        // ---- cond -> bf16 B fragments ----
        short8 cfa, cfb;
        cfa[0]=f2bf(cAa.x); cfa[1]=f2bf(cAa.y); cfa[2]=f2bf(cAa.z); cfa[3]=f2bf(cAa.w);
        cfa[4]=f2bf(cBa.x); cfa[5]=f2bf(cBa.y); cfa[6]=f2bf(cBa.z); cfa[7]=f2bf(cBa.w);
        cfb[0]=f2bf(cAb.x); cfb[1]=f2bf(cAb.y); cfb[2]=f2bf(cAb.z); cfb[3]=f2bf(cAb.w);
        cfb[4]=f2bf(cBb.x); cfb[5]=f2bf(cBb.y); cfb[6]=f2bf(cBb.z); cfb[7]=f2bf(cBb.w);

        // ---- x1 as B fragment for bias term ----
        #define MAKE_XB(xb, x0, x1, x2, x3) do {                                        \
            if (quad == 0) {                                                            \
                xb[0]=f2bf(x0.x); xb[1]=f2bf(x0.y); xb[2]=f2bf(x0.z); xb[3]=f2bf(x0.w); \
                xb[4]=f2bf(x1.x); xb[5]=f2bf(x1.y); xb[6]=f2bf(x1.z); xb[7]=f2bf(x1.w); \
            } else if (quad == 1) {                                                     \
                xb[0]=f2bf(x2.x); xb[1]=f2bf(x2.y); xb[2]=f2bf(x2.z); xb[3]=f2bf(x2.w); \
                xb[4]=f2bf(x3.x); xb[5]=f2bf(x3.y); xb[6]=f2bf(x3.z); xb[7]=f2bf(x3.w); \
            } else if (quad == 2) {                                                     \
                xb[0]=f2bf(1.0f); xb[1]=0; xb[2]=0; xb[3]=0;                            \
                xb[4]=0; xb[5]=0; xb[6]=0; xb[7]=0;                                     \
            } else {                                                                    \
                xb[0]=0; xb[1]=0; xb[2]=0; xb[3]=0;                                     \
                xb[4]=0; xb[5]=0; xb[6]=0; xb[7]=0;                                     \
            }                                                                           \
        } while (0)
        short8 xba, xbb;
        MAKE_XB(xba, x0a, x1a, x2a, x3a);
        MAKE_XB(xbb, x0b, x1b, x2b, x3b);
        #undef MAKE_XB

        // ---- bias MFMAs initialize accumulators ----
        floatx4 fa0 = __builtin_amdgcn_mfma_f32_16x16x32_bf16(bA0, xba, zero, 0, 0, 0);
        floatx4 fa1 = __builtin_amdgcn_mfma_f32_16x16x32_bf16(bA1, xba, zero, 0, 0, 0);
        floatx4 fb0 = __builtin_amdgcn_mfma_f32_16x16x32_bf16(bA0, xbb, zero, 0, 0, 0);
        floatx4 fb1 = __builtin_amdgcn_mfma_f32_16x16x32_bf16(bA1, xbb, zero, 0, 0, 0);

        // ---- 17 steps: 2 ds_read_b128 serve 4 MFMAs (both tiles) ----
        #define STEP(i, sa, sb) do {                                                       \
            short8 w0 = lds_w[(i) * 128 + lane];                                           \
            short8 w1 = lds_w[(i) * 128 + 64 + lane];                                      \
            floatx4 d00 = __builtin_amdgcn_mfma_f32_16x16x32_bf16(w0, cfa, zero, 0, 0, 0); \
            floatx4 d01 = __builtin_amdgcn_mfma_f32_16x16x32_bf16(w1, cfa, zero, 0, 0, 0); \
            floatx4 d10 = __builtin_amdgcn_mfma_f32_16x16x32_bf16(w0, cfb, zero, 0, 0, 0); \
            floatx4 d11 = __builtin_amdgcn_mfma_f32_16x16x32_bf16(w1, cfb, zero, 0, 0, 0); \
            fa0 += d00 * (sa); fa1 += d01 * (sa);                                          \
            fb0 += d10 * (sb); fb1 += d11 * (sb);                                          \
        } while (0)
        STEP(0,  x0a.x, x0b.x); STEP(1,  x0a.y, x0b.y);
        STEP(2,  x0a.z, x0b.z); STEP(3,  x0a.w, x0b.w);
        STEP(4,  x1a.x, x1b.x); STEP(5,  x1a.y, x1b.y);
        STEP(6,  x1a.z, x1b.z); STEP(7,  x1a.w, x1b.w);
        STEP(8,  x2a.x, x2b.x); STEP(9,  x2a.y, x2b.y);
        STEP(10, x2a.z, x2b.z); STEP(11, x2a.w, x2b.w);
        STEP(12, x3a.x, x3b.x); STEP(13, x3a.y, x3b.y);
        STEP(14, x3a.z, x3b.z); STEP(15, x3a.w, x3b.w);
        STEP(16, 1.0f,  1.0f);
        #undef STEP

        // ---- stores: lane writes 2x16B; wave covers full 128B rows ----
        float* da = outh + (size_t)(ba + r) * OUTF + quad * 4;
        __builtin_nontemporal_store(fa0, (floatx4*)da);
        __builtin_nontemporal_store(fa1, (floatx4*)(da + 16));
        float* db = outh + (size_t)(bb + r) * OUTF + quad * 4;
        __builtin_nontemporal_store(fb0, (floatx4*)db);
        __builtin_nontemporal_store(fb1, (floatx4*)(db + 16));
    }
}

extern "C" void kernel_launch(void* const* d_in, const int* in_sizes, int n_in,
                              void* d_out, int out_size, void* d_ws, size_t ws_size,
                              hipStream_t stream) {
    const float* input  = (const float*)d_in[0];
    const float* cond   = (const float*)d_in[1];
    const float* weight = (const float*)d_in[2];
    const float* bias   = (const float*)d_in[3];
    float* out = (float*)d_out;
    short8* ws = (short8*)d_ws;   // needs (NH*WELEM + NH*BELEM)*16 = 294912 B

    hipLaunchKernelGGL(prep_w, dim3(4, NH, 1), dim3(256, 1, 1), 0, stream,
                       weight, bias, ws);
    hipLaunchKernelGGL(meta_multilinear, dim3(BLKX, NH, 1), dim3(256, 1, 1), 0, stream,
                       input, cond, ws, out);
}

// Round 7
// 112.748 us; speedup vs baseline: 1.5038x; 1.0053x over previous
//
#include <hip/hip_runtime.h>

#define NH    8
#define BROWS 32768
#define INF   16
#define CIN   32
#define OUTF  32
#define KTOT  544   // OUTF*(INF+1)

#define BLKX  128                  // blocks per head -> 1024 total
#define WELEM 2176                 // W image elements (short8) per head: 17*2*64
#define BELEM 128                  // bias frag elements (short8) per head: 2*64

typedef __attribute__((ext_vector_type(8))) short short8;
typedef __attribute__((ext_vector_type(4))) float floatx4;

__device__ __forceinline__ short f2bf(float f) {
    __bf16 h = (__bf16)f;   // RNE f32->bf16
    return __builtin_bit_cast(short, h);
}

// ---------------- prep: W,bias -> bf16 fragment images in d_ws ----------------
// ws layout: [h][s] W image (NH*WELEM short8), then [h][s] bias frags (NH*BELEM).
// W image element s: i = s>>7, ot = (s>>6)&1, lane sl = s&63 (sr = sl&15, sq = sl>>4)
//   holds A[m = ot*16+sr][k = sq*8 .. +8) = W[h][(ot*16+sr)*17 + i][sq*8 ..]
// bias element s: ot = s>>6, lane sl: holds bias[h][(ot*16+sr)*17 + (sq*8+j)], 0 pad i>=17.
__global__ __launch_bounds__(256) void prep_w(
    const float* __restrict__ weight,
    const float* __restrict__ bias,
    short8* __restrict__ ws)
{
    const int q = blockIdx.x;       // quarter 0..3
    const int h = blockIdx.y;
    const float* Wh = weight + (size_t)h * KTOT * CIN;
    short8* dstW = ws + (size_t)h * WELEM;

    for (int s = q * (WELEM / 4) + threadIdx.x; s < (q + 1) * (WELEM / 4); s += 256) {
        const int sl = s & 63;
        const int sr = sl & 15;
        const int sq = sl >> 4;
        const int ot = (s >> 6) & 1;
        const int i  = s >> 7;
        const float* src = Wh + (size_t)((ot * 16 + sr) * 17 + i) * CIN + sq * 8;
        floatx4 w0 = *(const floatx4*)(src);
        floatx4 w1 = *(const floatx4*)(src + 4);
        short8 f;
        f[0]=f2bf(w0.x); f[1]=f2bf(w0.y); f[2]=f2bf(w0.z); f[3]=f2bf(w0.w);
        f[4]=f2bf(w1.x); f[5]=f2bf(w1.y); f[6]=f2bf(w1.z); f[7]=f2bf(w1.w);
        dstW[s] = f;
    }

    if (q == 0) {
        const float* bh = bias + (size_t)h * KTOT;
        short8* dstB = ws + (size_t)NH * WELEM + (size_t)h * BELEM;
        for (int s = threadIdx.x; s < BELEM; s += 256) {
            const int sl = s & 63;
            const int sr = sl & 15;
            const int sq = sl >> 4;
            const int ot = s >> 6;
            const int o  = ot * 16 + sr;
            short8 f;
            #pragma unroll
            for (int j = 0; j < 8; ++j) {
                const int i = sq * 8 + j;
                f[j] = (i < 17) ? f2bf(bh[o * 17 + i]) : (short)0;
            }
            dstB[s] = f;
        }
    }
}

// ---------------- main ----------------
// Grid: (128, 8). Block: 256 threads = 4 independent waves. LDS: 34816 B.
// Each wave: 4 consecutive 16-sample tiles in ONE pass. All 24 global loads
// front-loaded (one vmcnt window), then one 17-step loop where each pair of
// ds_read_b128 feeds 8 MFMAs (4 tiles x 2 otiles) -- deep ILP per wave.
// Swapped MFMA: D[m=o][n=b] = W_i x cond^T; per-sample scale x1[b,i] applied
// to D (lane-local). Bias = accumulator-init MFMA. Full 128B out-lines,
// nontemporal stores.
__global__ __launch_bounds__(256) void meta_multilinear(
    const float* __restrict__ input,
    const float* __restrict__ cond,
    const short8* __restrict__ ws,
    float* __restrict__ out)
{
    __shared__ short8 lds_w[WELEM];   // 34816 B

    const int tid  = threadIdx.x;
    const int lane = tid & 63;
    const int wave = tid >> 6;      // 0..3
    const int r    = lane & 15;
    const int quad = lane >> 4;     // 0..3
    const int c0   = quad * 8;      // K-slice start

    const int h = blockIdx.y;

    // ---- coalesced staging of pre-swizzled bf16 W image ----
    const short8* srcW = ws + (size_t)h * WELEM;
    for (int s = tid; s < WELEM; s += 256) lds_w[s] = srcW[s];

    // ---- bias fragments (2 x 16B loads) ----
    const short8* srcB = ws + (size_t)NH * WELEM + (size_t)h * BELEM;
    const short8 bA0 = srcB[lane];
    const short8 bA1 = srcB[64 + lane];

    __syncthreads();

    const float* condh = cond  + (size_t)h * BROWS * CIN;
    const float* inh   = input + (size_t)h * BROWS * INF;
    float*       outh  = out   + (size_t)h * BROWS * OUTF;
    const floatx4 zero = {0.f, 0.f, 0.f, 0.f};

    const int gw = blockIdx.x * 4 + wave;   // 0..511 per head
    const int b0 = gw * 64;                 // 4 tiles: rows b0 + t*16

    // ---- front-load ALL 24 global loads (4 tiles x 6 dwordx4) ----
    #define LOADT(T, boff)                                                      \
        const float* crow##T = condh + (size_t)(b0 + (boff) + r) * CIN + c0;    \
        floatx4 cA##T = *(const floatx4*)(crow##T);                             \
        floatx4 cB##T = *(const floatx4*)(crow##T + 4);                         \
        const float* xrow##T = inh + (size_t)(b0 + (boff) + r) * INF;           \
        floatx4 x0##T = *(const floatx4*)(xrow##T);                             \
        floatx4 x1##T = *(const floatx4*)(xrow##T + 4);                         \
        floatx4 x2##T = *(const floatx4*)(xrow##T + 8);                         \
        floatx4 x3##T = *(const floatx4*)(xrow##T + 12);
    LOADT(0, 0)
    LOADT(1, 16)
    LOADT(2, 32)
    LOADT(3, 48)
    #undef LOADT

    // ---- cond -> bf16 B fragments ----
    #define MKCF(T)                                                                          \
        short8 cf##T;                                                                        \
        cf##T[0]=f2bf(cA##T.x); cf##T[1]=f2bf(cA##T.y); cf##T[2]=f2bf(cA##T.z); cf##T[3]=f2bf(cA##T.w); \
        cf##T[4]=f2bf(cB##T.x); cf##T[5]=f2bf(cB##T.y); cf##T[6]=f2bf(cB##T.z); cf##T[7]=f2bf(cB##T.w);
    MKCF(0) MKCF(1) MKCF(2) MKCF(3)
    #undef MKCF

    // ---- x1 as B fragment for bias term ----
    #define MKXB(T)                                                                              \
        short8 xb##T;                                                                            \
        if (quad == 0) {                                                                         \
            xb##T[0]=f2bf(x0##T.x); xb##T[1]=f2bf(x0##T.y); xb##T[2]=f2bf(x0##T.z); xb##T[3]=f2bf(x0##T.w); \
            xb##T[4]=f2bf(x1##T.x); xb##T[5]=f2bf(x1##T.y); xb##T[6]=f2bf(x1##T.z); xb##T[7]=f2bf(x1##T.w); \
        } else if (quad == 1) {                                                                  \
            xb##T[0]=f2bf(x2##T.x); xb##T[1]=f2bf(x2##T.y); xb##T[2]=f2bf(x2##T.z); xb##T[3]=f2bf(x2##T.w); \
            xb##T[4]=f2bf(x3##T.x); xb##T[5]=f2bf(x3##T.y); xb##T[6]=f2bf(x3##T.z); xb##T[7]=f2bf(x3##T.w); \
        } else if (quad == 2) {                                                                  \
            xb##T[0]=f2bf(1.0f); xb##T[1]=0; xb##T[2]=0; xb##T[3]=0;                             \
            xb##T[4]=0; xb##T[5]=0; xb##T[6]=0; xb##T[7]=0;                                      \
        } else {                                                                                 \
            xb##T[0]=0; xb##T[1]=0; xb##T[2]=0; xb##T[3]=0;                                      \
            xb##T[4]=0; xb##T[5]=0; xb##T[6]=0; xb##T[7]=0;                                      \
        }
    MKXB(0) MKXB(1) MKXB(2) MKXB(3)
    #undef MKXB

    // ---- bias MFMAs initialize accumulators (8 independent MFMAs) ----
    floatx4 f00 = __builtin_amdgcn_mfma_f32_16x16x32_bf16(bA0, xb0, zero, 0, 0, 0);
    floatx4 f01 = __builtin_amdgcn_mfma_f32_16x16x32_bf16(bA1, xb0, zero, 0, 0, 0);
    floatx4 f10 = __builtin_amdgcn_mfma_f32_16x16x32_bf16(bA0, xb1, zero, 0, 0, 0);
    floatx4 f11 = __builtin_amdgcn_mfma_f32_16x16x32_bf16(bA1, xb1, zero, 0, 0, 0);
    floatx4 f20 = __builtin_amdgcn_mfma_f32_16x16x32_bf16(bA0, xb2, zero, 0, 0, 0);
    floatx4 f21 = __builtin_amdgcn_mfma_f32_16x16x32_bf16(bA1, xb2, zero, 0, 0, 0);
    floatx4 f30 = __builtin_amdgcn_mfma_f32_16x16x32_bf16(bA0, xb3, zero, 0, 0, 0);
    floatx4 f31 = __builtin_amdgcn_mfma_f32_16x16x32_bf16(bA1, xb3, zero, 0, 0, 0);

    // ---- 17 steps: 2 ds_read_b128 feed 8 MFMAs + 16 pk_fma ----
    #define STEP(i, s0_, s1_, s2_, s3_) do {                                               \
        short8 w0 = lds_w[(i) * 128 + lane];                                               \
        short8 w1 = lds_w[(i) * 128 + 64 + lane];                                          \
        floatx4 d;                                                                         \
        d = __builtin_amdgcn_mfma_f32_16x16x32_bf16(w0, cf0, zero, 0, 0, 0); f00 += d * (s0_); \
        d = __builtin_amdgcn_mfma_f32_16x16x32_bf16(w1, cf0, zero, 0, 0, 0); f01 += d * (s0_); \
        d = __builtin_amdgcn_mfma_f32_16x16x32_bf16(w0, cf1, zero, 0, 0, 0); f10 += d * (s1_); \
        d = __builtin_amdgcn_mfma_f32_16x16x32_bf16(w1, cf1, zero, 0, 0, 0); f11 += d * (s1_); \
        d = __builtin_amdgcn_mfma_f32_16x16x32_bf16(w0, cf2, zero, 0, 0, 0); f20 += d * (s2_); \
        d = __builtin_amdgcn_mfma_f32_16x16x32_bf16(w1, cf2, zero, 0, 0, 0); f21 += d * (s2_); \
        d = __builtin_amdgcn_mfma_f32_16x16x32_bf16(w0, cf3, zero, 0, 0, 0); f30 += d * (s3_); \
        d = __builtin_amdgcn_mfma_f32_16x16x32_bf16(w1, cf3, zero, 0, 0, 0); f31 += d * (s3_); \
    } while (0)
    STEP(0,  x00.x, x01.x, x02.x, x03.x);
    STEP(1,  x00.y, x01.y, x02.y, x03.y);
    STEP(2,  x00.z, x01.z, x02.z, x03.z);
    STEP(3,  x00.w, x01.w, x02.w, x03.w);
    STEP(4,  x10.x, x11.x, x12.x, x13.x);
    STEP(5,  x10.y, x11.y, x12.y, x13.y);
    STEP(6,  x10.z, x11.z, x12.z, x13.z);
    STEP(7,  x10.w, x11.w, x12.w, x13.w);
    STEP(8,  x20.x, x21.x, x22.x, x23.x);
    STEP(9,  x20.y, x21.y, x22.y, x23.y);
    STEP(10, x20.z, x21.z, x22.z, x23.z);
    STEP(11, x20.w, x21.w, x22.w, x23.w);
    STEP(12, x30.x, x31.x, x32.x, x33.x);
    STEP(13, x30.y, x31.y, x32.y, x33.y);
    STEP(14, x30.z, x31.z, x32.z, x33.z);
    STEP(15, x30.w, x31.w, x32.w, x33.w);
    STEP(16, 1.0f,  1.0f,  1.0f,  1.0f);
    #undef STEP

    // ---- stores: lane writes 2x16B per tile; wave covers full 128B rows ----
    #define STORET(T, boff)                                                     \
        do {                                                                    \
            float* d_ = outh + (size_t)(b0 + (boff) + r) * OUTF + quad * 4;     \
            __builtin_nontemporal_store(f##T##0, (floatx4*)d_);                 \
            __builtin_nontemporal_store(f##T##1, (floatx4*)(d_ + 16));          \
        } while (0)
    STORET(0, 0);
    STORET(1, 16);
    STORET(2, 32);
    STORET(3, 48);
    #undef STORET
}

extern "C" void kernel_launch(void* const* d_in, const int* in_sizes, int n_in,
                              void* d_out, int out_size, void* d_ws, size_t ws_size,
                              hipStream_t stream) {
    const float* input  = (const float*)d_in[0];
    const float* cond   = (const float*)d_in[1];
    const float* weight = (const float*)d_in[2];
    const float* bias   = (const float*)d_in[3];
    float* out = (float*)d_out;
    short8* ws = (short8*)d_ws;   // needs (NH*WELEM + NH*BELEM)*16 = 294912 B

    hipLaunchKernelGGL(prep_w, dim3(4, NH, 1), dim3(256, 1, 1), 0, stream,
                       weight, bias, ws);
    hipLaunchKernelGGL(meta_multilinear, dim3(BLKX, NH, 1), dim3(256, 1, 1), 0, stream,
                       input, cond, ws, out);
}